// Round 9
// baseline (1365.717 us; speedup 1.0000x reference)
//
#include <hip/hip_runtime.h>
#include <hip/hip_cooperative_groups.h>

namespace cg = cooperative_groups;

// ---------------------------------------------------------------------------
// GCN block: 3 x (GCNConv -> ReLU -> global_mean_pool)
// Setup: ONE cooperative kernel (k_setup, 1024x256, grid.sync between phases):
//   p0: zero cnt + graph bounds (binary search) + WbT transpose/cast
//   p1: epos[e]=atomicAdd(cnt[col],1) (the only atomics) + x fp32->bf16 cast
//   p2: in-kernel scan  (1 node/thread, block shuffle-scan -> block0 -> add)
//   p3: csr[ptr[c]+epos[e]] = (row, ew)   (plain stores, L2-absorbed)
//   p4: dinv = rsqrt(1 + bucket weight sum)   (half-wave/node, coalesced)
//   p5: csr.y = dinv[r]*w*dinv[c]             (half-wave/node, L2-hot dinv)
// Per layer (regular dispatches, proven):
//   GEMM via v_mfma_f32_16x16x32_bf16 -> paired-edge gather-aggregate fp32
//   -> h bf16 -> segment pool per graph (no atomics).
// ---------------------------------------------------------------------------

typedef short short8 __attribute__((ext_vector_type(8)));   // 8 bf16 (4 VGPR)
typedef float f32x4  __attribute__((ext_vector_type(4)));   // MFMA C/D

#define SETUP_BLOCKS 1024

__device__ inline unsigned pack_bf16x2(float a, float b) {
    unsigned ua = __float_as_uint(a);
    ua = (ua + 0x7FFFu + ((ua >> 16) & 1u)) >> 16;       // RNE
    unsigned ub = __float_as_uint(b);
    ub = (ub + 0x7FFFu + ((ub >> 16) & 1u)) >> 16;
    return ua | (ub << 16);
}
__device__ inline ushort bf16_1(float a) {
    unsigned ua = __float_as_uint(a);
    return (ushort)((ua + 0x7FFFu + ((ua >> 16) & 1u)) >> 16);
}
__device__ inline float bf_lo(unsigned u) { return __uint_as_float(u << 16); }
__device__ inline float bf_hi(unsigned u) { return __uint_as_float(u & 0xFFFF0000u); }

__global__ __launch_bounds__(256) void k_setup(
        const int* __restrict__ ei, const float* __restrict__ ew,
        const int* __restrict__ batch,
        const float* __restrict__ W0, const float* __restrict__ W1,
        const float* __restrict__ W2, const float4* __restrict__ x4,
        int* __restrict__ cnt, int* __restrict__ ptrv, int* __restrict__ bsum,
        int* __restrict__ gb, float* __restrict__ dinv,
        ushort* __restrict__ WbT, uint2* __restrict__ xb2,
        int* __restrict__ epos, int2* __restrict__ csr,
        int N, int E, int G) {
    cg::grid_group grid = cg::this_grid();
    const int tid = blockIdx.x * 256 + threadIdx.x;
    const int nthr = SETUP_BLOCKS * 256;               // 262144 >= N

    // ---- phase 0: zero cnt, graph bounds, WbT prep ----
    for (int i = tid; i < N; i += nthr) cnt[i] = 0;
    if (tid <= G) {
        int lo = 0, hi = N;
        while (lo < hi) { int mid = (lo + hi) >> 1; if (batch[mid] < tid) lo = mid + 1; else hi = mid; }
        gb[tid] = lo;
    }
    for (int i = tid; i < 3 * 16384; i += nthr) {
        int l = i >> 14;
        const float* W = (l == 0) ? W0 : ((l == 1) ? W1 : W2);
        int id2 = i & 16383;
        int n = id2 & 127, k = id2 >> 7;
        WbT[l * 16384 + n * 128 + k] = bf16_1(W[k * 128 + n]);
    }
    grid.sync();

    // ---- phase 1: atomic bucket ranks + x cast ----
    for (int e = tid; e < E; e += nthr)
        epos[e] = atomicAdd(&cnt[ei[E + e]], 1);
    for (int i = tid; i < N * 32; i += nthr) {
        float4 f = x4[i];
        uint2 v;
        v.x = pack_bf16x2(f.x, f.y);
        v.y = pack_bf16x2(f.z, f.w);
        xb2[i] = v;
    }
    grid.sync();

    // ---- phase 2: exclusive scan of cnt -> ptrv (one element per thread) ----
    __shared__ int wsum[4];
    __shared__ int btot[256];
    int lane = threadIdx.x & 63, w = threadIdx.x >> 6;
    int v = (tid < N) ? cnt[tid] : 0;
    int x = v;
#pragma unroll
    for (int off = 1; off < 64; off <<= 1) {
        int y = __shfl_up(x, off, 64);
        if (lane >= off) x += y;
    }
    if (lane == 63) wsum[w] = x;
    __syncthreads();
    int woff = 0, tot = 0;
#pragma unroll
    for (int q = 0; q < 4; q++) { int s = wsum[q]; if (q < w) woff += s; tot += s; }
    int myPre = woff + x - v;                          // exclusive within block
    if (threadIdx.x == 0) bsum[blockIdx.x] = tot;
    grid.sync();

    if (blockIdx.x == 0) {                             // scan the 1024 partials
        int t = threadIdx.x;
        int b4[4];
#pragma unroll
        for (int q = 0; q < 4; q++) b4[q] = bsum[t * 4 + q];
        int s4 = b4[0] + b4[1] + b4[2] + b4[3];
        int xx = s4;
#pragma unroll
        for (int off = 1; off < 64; off <<= 1) {
            int y = __shfl_up(xx, off, 64);
            if (lane >= off) xx += y;
        }
        if (lane == 63) btot[w] = xx;                  // reuse btot[0..3]
        __syncthreads();
        int woff2 = 0;
#pragma unroll
        for (int q = 0; q < 4; q++) { if (q < w) woff2 += btot[q]; }
        int off0 = woff2 + xx - s4;                    // exclusive over thread t
        int run = off0;
#pragma unroll
        for (int q = 0; q < 4; q++) { int bv = b4[q]; bsum[t * 4 + q] = run; run += bv; }
        if (t == 255) ptrv[N] = run;                   // grand total
    }
    grid.sync();
    if (tid < N) ptrv[tid] = myPre + bsum[blockIdx.x];
    grid.sync();

    // ---- phase 3: scatter edges into CSR slots ----
    for (int e = tid; e < E; e += nthr) {
        int r = ei[e];
        int c = ei[E + e];
        int2 m; m.x = r; m.y = __float_as_int(ew[e]);
        csr[ptrv[c] + epos[e]] = m;
    }
    grid.sync();

    // ---- phase 4: deg -> dinv (half-wave per node, coalesced) ----
    int hw = tid >> 5;                                 // global half-wave id
    int j = threadIdx.x & 31;
    int nhw = nthr >> 5;                               // 8192
    for (int node = hw; node < N; node += nhw) {
        int e0 = ptrv[node], e1 = ptrv[node + 1];
        float s = (j == 0) ? 1.0f : 0.0f;
        for (int e = e0 + j; e < e1; e += 32) s += __int_as_float(csr[e].y);
#pragma unroll
        for (int off = 1; off < 32; off <<= 1) s += __shfl_xor(s, off, 64);
        if (j == 0) dinv[node] = rsqrtf(s);
    }
    grid.sync();

    // ---- phase 5: csr.y = dinv[r] * w * dinv[c] ----
    for (int node = hw; node < N; node += nhw) {
        float dc = dinv[node];
        int e0 = ptrv[node], e1 = ptrv[node + 1];
        for (int e = e0 + j; e < e1; e += 32) {
            int2 m = csr[e];
            m.y = __float_as_int(dinv[m.x] * __int_as_float(m.y) * dc);
            csr[e] = m;
        }
    }
}

// hl = H @ W via v_mfma_f32_16x16x32_bf16. Wave = 32 rows x 128 cols:
// 2 m-strips x 8 n-tiles, 64 MFMAs. A-frag: A[m=lane&15][k=quad*8+j] ->
// 16 B/lane contiguous from bf16-packed H. B-frag: B[k=quad*8+j][n=lane&15]
// -> 16 B/lane contiguous from WbT[n][k]. Epilogue via LDS -> coalesced u32.
__global__ __launch_bounds__(256) void k_gemm_mfma(const unsigned* __restrict__ Hb,
                                                   const ushort* __restrict__ WbT,
                                                   unsigned* __restrict__ O, int M) {
    __shared__ unsigned sOut[4 * 32 * 64];     // 32 KB: 4 waves x 32 rows x 128 bf16
    int lane = threadIdx.x & 63;
    int wv = threadIdx.x >> 6;
    int quad = lane >> 4;
    int mrow = lane & 15;
    int m0 = blockIdx.x * 128 + wv * 32;
    int r0 = m0 + mrow;
    int r1 = r0 + 16;
    int r0c = r0 < M ? r0 : M - 1;             // clamp loads, guard stores
    int r1c = r1 < M ? r1 : M - 1;

    short8 a0[4], a1[4];
#pragma unroll
    for (int s = 0; s < 4; s++) {              // k-step s covers k in [32s,32s+32)
        a0[s] = *(const short8*)(Hb + (size_t)r0c * 64 + s * 16 + quad * 4);
        a1[s] = *(const short8*)(Hb + (size_t)r1c * 64 + s * 16 + quad * 4);
    }
    f32x4 acc0[8], acc1[8];
#pragma unroll
    for (int t = 0; t < 8; t++) {
        acc0[t] = (f32x4){0.f, 0.f, 0.f, 0.f};
        acc1[t] = (f32x4){0.f, 0.f, 0.f, 0.f};
    }
#pragma unroll
    for (int s = 0; s < 4; s++) {
#pragma unroll
        for (int t = 0; t < 8; t++) {
            short8 b = *(const short8*)(WbT + (t * 16 + mrow) * 128 + s * 32 + quad * 8);
            acc0[t] = __builtin_amdgcn_mfma_f32_16x16x32_bf16(a0[s], b, acc0[t], 0, 0, 0);
            acc1[t] = __builtin_amdgcn_mfma_f32_16x16x32_bf16(a1[s], b, acc1[t], 0, 0, 0);
        }
    }
    // C/D layout: col = lane&15, row = quad*4 + reg. Write bf16 to LDS, read
    // back row-major for coalesced u32 global stores.
    ushort* so = (ushort*)(sOut + wv * 32 * 64);
#pragma unroll
    for (int t = 0; t < 8; t++) {
#pragma unroll
        for (int r = 0; r < 4; r++) {
            int lr = quad * 4 + r;
            int c = t * 16 + mrow;
            so[lr * 128 + c] = bf16_1(acc0[t][r]);
            so[(lr + 16) * 128 + c] = bf16_1(acc1[t][r]);
        }
    }
    __syncthreads();
    const unsigned* si = sOut + wv * 32 * 64;
#pragma unroll 8
    for (int r = 0; r < 32; r++) {
        int row = m0 + r;
        if (row < M) O[(size_t)row * 64 + lane] = si[r * 64 + lane];
    }
}

// One wave per node, paired-edge: lanes 0-31 take even edges, lanes 32-63 odd
// edges of the SAME node (no divergence). Each lane loads uint2 (4 features),
// so one load instruction fetches two 256B rows. Cross-half shfl_xor(32)
// merges the partials; half 0 stores.
__global__ __launch_bounds__(256) void k_agg(const unsigned* __restrict__ HL,
                                             const int* __restrict__ ptr,
                                             const int2* __restrict__ csr,
                                             const float* __restrict__ dinv,
                                             const float* __restrict__ bias,
                                             unsigned* __restrict__ Hout, int M) {
    __shared__ int2 sM[4 * 64];
    int node = (int)((blockIdx.x * blockDim.x + threadIdx.x) >> 6);
    if (node >= M) return;
    int lane = threadIdx.x & 63;
    int half = lane >> 5;                 // 0: even edges, 1: odd edges
    int q = lane & 31;                    // features 4q .. 4q+3
    int2* mbase = &sM[(threadIdx.x >> 6) * 64];
    int e0 = ptr[node], e1 = ptr[node + 1];
    int deg = e1 - e0;
    int nbv = deg < 64 ? deg : 64;
    if (lane < nbv) mbase[lane] = csr[e0 + lane];   // one coalesced load
    const uint2* HL2 = (const uint2*)HL;            // row = 32 uint2
    float di = dinv[node];
    float sn = (half == 0) ? di * di : 0.f;         // self-loop on half 0 only
    uint2 us = HL2[(size_t)node * 32 + q];          // both halves same lines
    float a0 = sn * bf_lo(us.x), a1 = sn * bf_hi(us.x);
    float a2 = sn * bf_lo(us.y), a3 = sn * bf_hi(us.y);
    int j = half;
    for (; j + 8 <= nbv; j += 8) {                  // 4 pairs in flight
        int2 m[4]; uint2 u[4];
#pragma unroll
        for (int t = 0; t < 4; t++) m[t] = mbase[j + 2 * t];
#pragma unroll
        for (int t = 0; t < 4; t++) u[t] = HL2[(size_t)m[t].x * 32 + q];
#pragma unroll
        for (int t = 0; t < 4; t++) {
            float nv = __int_as_float(m[t].y);
            a0 += nv * bf_lo(u[t].x); a1 += nv * bf_hi(u[t].x);
            a2 += nv * bf_lo(u[t].y); a3 += nv * bf_hi(u[t].y);
        }
    }
    for (; j < nbv; j += 2) {
        int2 m = mbase[j];
        uint2 u = HL2[(size_t)m.x * 32 + q];
        float nv = __int_as_float(m.y);
        a0 += nv * bf_lo(u.x); a1 += nv * bf_hi(u.x);
        a2 += nv * bf_lo(u.y); a3 += nv * bf_hi(u.y);
    }
    for (int e = e0 + 64 + half; e < e1; e += 2) {  // rare high-degree tail
        int2 m = csr[e];
        uint2 u = HL2[(size_t)m.x * 32 + q];
        float nv = __int_as_float(m.y);
        a0 += nv * bf_lo(u.x); a1 += nv * bf_hi(u.x);
        a2 += nv * bf_lo(u.y); a3 += nv * bf_hi(u.y);
    }
    a0 += __shfl_xor(a0, 32, 64);
    a1 += __shfl_xor(a1, 32, 64);
    a2 += __shfl_xor(a2, 32, 64);
    a3 += __shfl_xor(a3, 32, 64);
    float4 bv = ((const float4*)bias)[q];
    float r0 = fmaxf(a0 + bv.x, 0.f);
    float r1 = fmaxf(a1 + bv.y, 0.f);
    float r2 = fmaxf(a2 + bv.z, 0.f);
    float r3 = fmaxf(a3 + bv.w, 0.f);
    if (half == 0) {
        uint2 pv;
        pv.x = pack_bf16x2(r0, r1);
        pv.y = pack_bf16x2(r2, r3);
        ((uint2*)(Hout + (size_t)node * 64))[q] = pv;
    }
}

// One block per graph: stream the sorted node segment, 4 waves stride it,
// LDS-combine, divide by count, write. No atomics.
__global__ __launch_bounds__(256) void k_pool(const unsigned* __restrict__ HB,
                                              const int* __restrict__ gb,
                                              float* __restrict__ outp) {
    __shared__ float part[4][128];
    int g = blockIdx.x;
    int lane = threadIdx.x & 63, w = threadIdx.x >> 6;
    int s = gb[g], e = gb[g + 1];
    float ax = 0.f, ay = 0.f;
    for (int i = s + w; i < e; i += 4) {
        unsigned u = HB[(size_t)i * 64 + lane];
        ax += bf_lo(u); ay += bf_hi(u);
    }
    part[w][lane * 2] = ax;
    part[w][lane * 2 + 1] = ay;
    __syncthreads();
    if (threadIdx.x < 128) {
        float sum = part[0][threadIdx.x] + part[1][threadIdx.x]
                  + part[2][threadIdx.x] + part[3][threadIdx.x];
        float c = (float)(e - s);
        outp[g * 128 + threadIdx.x] = sum / fmaxf(c, 1.0f);
    }
}

extern "C" void kernel_launch(void* const* d_in, const int* in_sizes, int n_in,
                              void* d_out, int out_size, void* d_ws, size_t ws_size,
                              hipStream_t stream) {
    const float* x     = (const float*)d_in[0];
    const int*   ei    = (const int*)d_in[1];
    const float* ew    = (const float*)d_in[2];
    const int*   batch = (const int*)d_in[3];
    const float* W0 = (const float*)d_in[4];
    const float* W1 = (const float*)d_in[6];
    const float* W2 = (const float*)d_in[8];
    const float* bt[3] = {(const float*)d_in[5], (const float*)d_in[7], (const float*)d_in[9]};
    float* out = (float*)d_out;

    const int D = 128;
    int N = in_sizes[0] / D;       // 100000
    int E = in_sizes[2];           // 1600000
    int G = out_size / (3 * D);    // 256

    // workspace carve-up (256 B aligned)
    char* p = (char*)d_ws;
    auto alloc = [&](size_t bytes) {
        void* r = (void*)p;
        p += (bytes + 255) & ~(size_t)255;
        return r;
    };
    int*      cnt    = (int*)alloc((size_t)N * 4);
    int*      ptr    = (int*)alloc((size_t)(N + 1) * 4);
    int*      bsum   = (int*)alloc((size_t)SETUP_BLOCKS * 4);
    int*      gb     = (int*)alloc((size_t)(G + 1) * 4);
    float*    dinv   = (float*)alloc((size_t)N * 4);
    ushort*   WbT    = (ushort*)alloc((size_t)3 * 16384 * 2);
    int2*     csr    = (int2*)alloc((size_t)E * 8);
    unsigned* xb     = (unsigned*)alloc((size_t)N * 64 * 4);  // x,  bf16-packed
    unsigned* bufHL  = (unsigned*)alloc((size_t)N * 64 * 4);  // hl, bf16-packed
    unsigned* bufH   = (unsigned*)alloc((size_t)N * 64 * 4);  // h,  bf16-packed
    int*      epos   = (int*)bufH;   // alias: epos dead before bufH first write

    const float4* x4 = (const float4*)x;
    uint2* xb2 = (uint2*)xb;
    void* args[] = {
        (void*)&ei, (void*)&ew, (void*)&batch,
        (void*)&W0, (void*)&W1, (void*)&W2, (void*)&x4,
        (void*)&cnt, (void*)&ptr, (void*)&bsum, (void*)&gb, (void*)&dinv,
        (void*)&WbT, (void*)&xb2, (void*)&epos, (void*)&csr,
        (void*)&N, (void*)&E, (void*)&G
    };
    hipLaunchCooperativeKernel((const void*)k_setup, dim3(SETUP_BLOCKS), dim3(256),
                               args, 0, stream);

    for (int l = 0; l < 3; l++) {
        const unsigned* hin = (l == 0) ? xb : bufH;
        k_gemm_mfma<<<(N + 127) / 128, 256, 0, stream>>>(hin, WbT + (size_t)l * 16384,
                                                         bufHL, N);
        k_agg<<<(N + 3) / 4, 256, 0, stream>>>(bufHL, ptr, csr, dinv, bt[l], bufH, N);
        k_pool<<<G, 256, 0, stream>>>(bufH, gb, out + (size_t)l * G * D);
    }
}

// Round 10
// 613.247 us; speedup vs baseline: 2.2270x; 2.2270x over previous
//
#include <hip/hip_runtime.h>

// ---------------------------------------------------------------------------
// GCN block: 3 x (GCNConv -> ReLU -> global_mean_pool)
// Setup (ONE atomic stream total; plain dispatches — cooperative grid.sync
// measured ~100us/sync on 8-XCD MI355X (R9), dispatch gaps are cheaper):
//   k_prep:   zero cnt + graph bounds (binary search) + WbT prep  (fused)
//   k_phase1: epos[e]=atomicAdd(cnt[col],1)  (only atomics, 1.6M)
//             + grid-stride fp32->bf16 cast of x (hidden under atomic latency)
//   k_scan1/2: block scan + block-sum scan (pre, bsum)
//   k_scatter: csr[pre[c]+bsum[c>>10]+epos[e]]=(row,ew); also materializes
//              ptrv[i]=pre[i]+bsum[i>>10] for downstream kernels (scan3 folded)
//   k_degdinv: half-wave per node, coalesced bucket reads, shfl reduce
//   k_norm:    half-wave per node, coalesced int2 RMW, L2-hot dinv gathers
// Per layer:
//   GEMM via v_mfma_f32_16x16x32_bf16 (all bf16-packed inputs)
//   -> gather-aggregate fp32, paired-edge half-waves, uint2/lane, 8 loads
//      in flight (mean degree 16 = one unrolled batch)
//   -> h bf16 -> segment pool per graph (no atomics).
// ---------------------------------------------------------------------------

typedef short short8 __attribute__((ext_vector_type(8)));   // 8 bf16 (4 VGPR)
typedef float f32x4  __attribute__((ext_vector_type(4)));   // MFMA C/D

__device__ inline unsigned pack_bf16x2(float a, float b) {
    unsigned ua = __float_as_uint(a);
    ua = (ua + 0x7FFFu + ((ua >> 16) & 1u)) >> 16;       // RNE
    unsigned ub = __float_as_uint(b);
    ub = (ub + 0x7FFFu + ((ub >> 16) & 1u)) >> 16;
    return ua | (ub << 16);
}
__device__ inline ushort bf16_1(float a) {
    unsigned ua = __float_as_uint(a);
    return (ushort)((ua + 0x7FFFu + ((ua >> 16) & 1u)) >> 16);
}
__device__ inline float bf_lo(unsigned u) { return __uint_as_float(u << 16); }
__device__ inline float bf_hi(unsigned u) { return __uint_as_float(u & 0xFFFF0000u); }

// Fused pre-pass: zero cnt, graph bounds, W transpose+cast. Independent jobs.
__global__ void k_prep(int* __restrict__ cnt, int N,
                       const int* __restrict__ batch, int* __restrict__ gb, int G,
                       const float* __restrict__ W0, const float* __restrict__ W1,
                       const float* __restrict__ W2, ushort* __restrict__ WbT) {
    int id = blockIdx.x * blockDim.x + threadIdx.x;
    if (id < N) cnt[id] = 0;
    if (id <= G) {
        int lo = 0, hi = N;
        while (lo < hi) { int mid = (lo + hi) >> 1; if (batch[mid] < id) lo = mid + 1; else hi = mid; }
        gb[id] = lo;
    }
    if (id < 3 * 16384) {
        int l = id >> 14;
        const float* W = (l == 0) ? W0 : ((l == 1) ? W1 : W2);
        int id2 = id & 16383;
        int n = id2 & 127, k = id2 >> 7;
        WbT[l * 16384 + n * 128 + k] = bf16_1(W[k * 128 + n]);
    }
}

// The ONLY atomic kernel: per-edge rank within its destination bucket.
// Also streams the x fp32->bf16 cast (hidden under atomic latency).
__global__ void k_phase1(const int* __restrict__ ei, int* __restrict__ cnt,
                         int* __restrict__ epos, int E,
                         const float4* __restrict__ x4, uint2* __restrict__ xb2,
                         int nCast) {
    int tid = blockIdx.x * blockDim.x + threadIdx.x;
    if (tid < E) {
        int c = ei[E + tid];
        epos[tid] = atomicAdd(&cnt[c], 1);
    }
    int stride = gridDim.x * blockDim.x;
    for (int i = tid; i < nCast; i += stride) {
        float4 f = x4[i];
        uint2 v;
        v.x = pack_bf16x2(f.x, f.y);
        v.y = pack_bf16x2(f.z, f.w);
        xb2[i] = v;
    }
}

// --- exclusive scan: scan1 (per-block pre) -> scan2 (block sums in place) ---
__global__ __launch_bounds__(1024) void k_scan1(const int* __restrict__ cnt,
                                                int* __restrict__ pre,
                                                int* __restrict__ bsum, int n) {
    __shared__ int wsum[16];
    int t = threadIdx.x, lane = t & 63, w = t >> 6;
    int i = blockIdx.x * 1024 + t;
    int v = (i < n) ? cnt[i] : 0;
    int x = v;
#pragma unroll
    for (int off = 1; off < 64; off <<= 1) {
        int y = __shfl_up(x, off, 64);
        if (lane >= off) x += y;
    }
    if (lane == 63) wsum[w] = x;
    __syncthreads();
    int woff = 0, tot = 0;
#pragma unroll
    for (int q = 0; q < 16; q++) { int s = wsum[q]; if (q < w) woff += s; tot += s; }
    if (i < n) pre[i] = woff + x - v;
    if (t == 0) bsum[blockIdx.x] = tot;
}

__global__ __launch_bounds__(128) void k_scan2(int* __restrict__ bsum, int nb,
                                               int* __restrict__ ptrv, int n) {
    __shared__ int ws[2];
    int t = threadIdx.x, lane = t & 63, w = t >> 6;
    int v = (t < nb) ? bsum[t] : 0;
    int x = v;
#pragma unroll
    for (int off = 1; off < 64; off <<= 1) {
        int y = __shfl_up(x, off, 64);
        if (lane >= off) x += y;
    }
    if (lane == 63) ws[w] = x;
    __syncthreads();
    int woff = (w == 1) ? ws[0] : 0;
    int tot = ws[0] + ws[1];
    if (t < nb) bsum[t] = woff + x - v;
    if (t == 0) ptrv[n] = tot;
}

// Scatter edges to CSR slots (plain stores; csr fits aggregate L2).
// Slot = pre[c] + bsum[c>>10] + epos[e]. Also materializes ptrv[i] for the
// downstream kernels (former scan3, folded here; races are benign since
// this kernel never reads ptrv).
__global__ void k_scatter(const int* __restrict__ ei, const float* __restrict__ ew,
                          const int* __restrict__ pre, const int* __restrict__ bsum,
                          int* __restrict__ ptrv, const int* __restrict__ epos,
                          int2* __restrict__ csr, int E, int N) {
    int e = blockIdx.x * blockDim.x + threadIdx.x;
    if (e < N) ptrv[e] = pre[e] + bsum[e >> 10];    // ptrv[N] written by scan2
    if (e >= E) return;
    int r = ei[e];
    int c = ei[E + e];
    int2 v; v.x = r; v.y = __float_as_int(ew[e]);
    csr[pre[c] + bsum[c >> 10] + epos[e]] = v;
}

// deg = 1 (self-loop) + sum of bucket weights; dinv = rsqrt(deg).
// Half-wave (32 lanes) per node: coalesced 256B bucket reads + shfl reduce.
__global__ __launch_bounds__(256) void k_degdinv(const int2* __restrict__ csr,
                                                 const int* __restrict__ ptrv,
                                                 float* __restrict__ dinv, int N) {
    int node = blockIdx.x * 8 + (threadIdx.x >> 5);
    int j = threadIdx.x & 31;
    if (node >= N) return;
    int e0 = ptrv[node], e1 = ptrv[node + 1];
    float s = (j == 0) ? 1.0f : 0.0f;
    for (int e = e0 + j; e < e1; e += 32) s += __int_as_float(csr[e].y);
#pragma unroll
    for (int off = 1; off < 32; off <<= 1) s += __shfl_xor(s, off, 64);
    if (j == 0) dinv[node] = rsqrtf(s);
}

// csr.y = dinv[r] * w * dinv[c]. Half-wave per node: coalesced int2 RMW,
// dinv[r] gathers are L2-hot (400 KB array).
__global__ __launch_bounds__(256) void k_norm(int2* __restrict__ csr,
                                              const int* __restrict__ ptrv,
                                              const float* __restrict__ dinv, int N) {
    int node = blockIdx.x * 8 + (threadIdx.x >> 5);
    int j = threadIdx.x & 31;
    if (node >= N) return;
    float dc = dinv[node];
    int e0 = ptrv[node], e1 = ptrv[node + 1];
    for (int e = e0 + j; e < e1; e += 32) {
        int2 m = csr[e];
        m.y = __float_as_int(dinv[m.x] * __int_as_float(m.y) * dc);
        csr[e] = m;
    }
}

// hl = H @ W via v_mfma_f32_16x16x32_bf16. Wave = 32 rows x 128 cols:
// 2 m-strips x 8 n-tiles, 64 MFMAs. A-frag: A[m=lane&15][k=quad*8+j] ->
// 16 B/lane contiguous from bf16-packed H. B-frag: B[k=quad*8+j][n=lane&15]
// -> 16 B/lane contiguous from WbT[n][k]. Epilogue via LDS -> coalesced u32.
__global__ __launch_bounds__(256) void k_gemm_mfma(const unsigned* __restrict__ Hb,
                                                   const ushort* __restrict__ WbT,
                                                   unsigned* __restrict__ O, int M) {
    __shared__ unsigned sOut[4 * 32 * 64];     // 32 KB: 4 waves x 32 rows x 128 bf16
    int lane = threadIdx.x & 63;
    int wv = threadIdx.x >> 6;
    int quad = lane >> 4;
    int mrow = lane & 15;
    int m0 = blockIdx.x * 128 + wv * 32;
    int r0 = m0 + mrow;
    int r1 = r0 + 16;
    int r0c = r0 < M ? r0 : M - 1;             // clamp loads, guard stores
    int r1c = r1 < M ? r1 : M - 1;

    short8 a0[4], a1[4];
#pragma unroll
    for (int s = 0; s < 4; s++) {              // k-step s covers k in [32s,32s+32)
        a0[s] = *(const short8*)(Hb + (size_t)r0c * 64 + s * 16 + quad * 4);
        a1[s] = *(const short8*)(Hb + (size_t)r1c * 64 + s * 16 + quad * 4);
    }
    f32x4 acc0[8], acc1[8];
#pragma unroll
    for (int t = 0; t < 8; t++) {
        acc0[t] = (f32x4){0.f, 0.f, 0.f, 0.f};
        acc1[t] = (f32x4){0.f, 0.f, 0.f, 0.f};
    }
#pragma unroll
    for (int s = 0; s < 4; s++) {
#pragma unroll
        for (int t = 0; t < 8; t++) {
            short8 b = *(const short8*)(WbT + (t * 16 + mrow) * 128 + s * 32 + quad * 8);
            acc0[t] = __builtin_amdgcn_mfma_f32_16x16x32_bf16(a0[s], b, acc0[t], 0, 0, 0);
            acc1[t] = __builtin_amdgcn_mfma_f32_16x16x32_bf16(a1[s], b, acc1[t], 0, 0, 0);
        }
    }
    // C/D layout: col = lane&15, row = quad*4 + reg. Write bf16 to LDS, read
    // back row-major for coalesced u32 global stores.
    ushort* so = (ushort*)(sOut + wv * 32 * 64);
#pragma unroll
    for (int t = 0; t < 8; t++) {
#pragma unroll
        for (int r = 0; r < 4; r++) {
            int lr = quad * 4 + r;
            int c = t * 16 + mrow;
            so[lr * 128 + c] = bf16_1(acc0[t][r]);
            so[(lr + 16) * 128 + c] = bf16_1(acc1[t][r]);
        }
    }
    __syncthreads();
    const unsigned* si = sOut + wv * 32 * 64;
#pragma unroll 8
    for (int r = 0; r < 32; r++) {
        int row = m0 + r;
        if (row < M) O[(size_t)row * 64 + lane] = si[r * 64 + lane];
    }
}

// One wave per node, paired-edge: lanes 0-31 take even edges, lanes 32-63 odd
// edges of the SAME node (no divergence). Each lane loads uint2 (4 features),
// so one load instruction fetches two 256B rows. Main loop keeps 8 loads in
// flight (16 edges/iter — one batch covers the mean degree). Cross-half
// shfl_xor(32) merges partials; half 0 stores. Accumulation order identical
// to the unpaired version per lane -> bit-stable.
__global__ __launch_bounds__(256) void k_agg(const unsigned* __restrict__ HL,
                                             const int* __restrict__ ptr,
                                             const int2* __restrict__ csr,
                                             const float* __restrict__ dinv,
                                             const float* __restrict__ bias,
                                             unsigned* __restrict__ Hout, int M) {
    __shared__ int2 sM[4 * 64];
    int node = (int)((blockIdx.x * blockDim.x + threadIdx.x) >> 6);
    if (node >= M) return;
    int lane = threadIdx.x & 63;
    int half = lane >> 5;                 // 0: even edges, 1: odd edges
    int q = lane & 31;                    // features 4q .. 4q+3
    int2* mbase = &sM[(threadIdx.x >> 6) * 64];
    int e0 = ptr[node], e1 = ptr[node + 1];
    int deg = e1 - e0;
    int nbv = deg < 64 ? deg : 64;
    if (lane < nbv) mbase[lane] = csr[e0 + lane];   // one coalesced load
    const uint2* HL2 = (const uint2*)HL;            // row = 32 uint2
    float di = dinv[node];
    float sn = (half == 0) ? di * di : 0.f;         // self-loop on half 0 only
    uint2 us = HL2[(size_t)node * 32 + q];          // both halves same lines
    float a0 = sn * bf_lo(us.x), a1 = sn * bf_hi(us.x);
    float a2 = sn * bf_lo(us.y), a3 = sn * bf_hi(us.y);
    int j = half;
    for (; j + 16 <= nbv; j += 16) {                // 8 pairs in flight
        int2 m[8]; uint2 u[8];
#pragma unroll
        for (int t = 0; t < 8; t++) m[t] = mbase[j + 2 * t];
#pragma unroll
        for (int t = 0; t < 8; t++) u[t] = HL2[(size_t)m[t].x * 32 + q];
#pragma unroll
        for (int t = 0; t < 8; t++) {
            float nv = __int_as_float(m[t].y);
            a0 += nv * bf_lo(u[t].x); a1 += nv * bf_hi(u[t].x);
            a2 += nv * bf_lo(u[t].y); a3 += nv * bf_hi(u[t].y);
        }
    }
    for (; j + 8 <= nbv; j += 8) {                  // 4 pairs in flight
        int2 m[4]; uint2 u[4];
#pragma unroll
        for (int t = 0; t < 4; t++) m[t] = mbase[j + 2 * t];
#pragma unroll
        for (int t = 0; t < 4; t++) u[t] = HL2[(size_t)m[t].x * 32 + q];
#pragma unroll
        for (int t = 0; t < 4; t++) {
            float nv = __int_as_float(m[t].y);
            a0 += nv * bf_lo(u[t].x); a1 += nv * bf_hi(u[t].x);
            a2 += nv * bf_lo(u[t].y); a3 += nv * bf_hi(u[t].y);
        }
    }
    for (; j < nbv; j += 2) {
        int2 m = mbase[j];
        uint2 u = HL2[(size_t)m.x * 32 + q];
        float nv = __int_as_float(m.y);
        a0 += nv * bf_lo(u.x); a1 += nv * bf_hi(u.x);
        a2 += nv * bf_lo(u.y); a3 += nv * bf_hi(u.y);
    }
    for (int e = e0 + 64 + half; e < e1; e += 2) {  // rare high-degree tail
        int2 m = csr[e];
        uint2 u = HL2[(size_t)m.x * 32 + q];
        float nv = __int_as_float(m.y);
        a0 += nv * bf_lo(u.x); a1 += nv * bf_hi(u.x);
        a2 += nv * bf_lo(u.y); a3 += nv * bf_hi(u.y);
    }
    a0 += __shfl_xor(a0, 32, 64);
    a1 += __shfl_xor(a1, 32, 64);
    a2 += __shfl_xor(a2, 32, 64);
    a3 += __shfl_xor(a3, 32, 64);
    float4 bv = ((const float4*)bias)[q];
    float r0 = fmaxf(a0 + bv.x, 0.f);
    float r1 = fmaxf(a1 + bv.y, 0.f);
    float r2 = fmaxf(a2 + bv.z, 0.f);
    float r3 = fmaxf(a3 + bv.w, 0.f);
    if (half == 0) {
        uint2 pv;
        pv.x = pack_bf16x2(r0, r1);
        pv.y = pack_bf16x2(r2, r3);
        ((uint2*)(Hout + (size_t)node * 64))[q] = pv;
    }
}

// One block per graph: stream the sorted node segment, 4 waves stride it,
// LDS-combine, divide by count, write. No atomics.
__global__ __launch_bounds__(256) void k_pool(const unsigned* __restrict__ HB,
                                              const int* __restrict__ gb,
                                              float* __restrict__ outp) {
    __shared__ float part[4][128];
    int g = blockIdx.x;
    int lane = threadIdx.x & 63, w = threadIdx.x >> 6;
    int s = gb[g], e = gb[g + 1];
    float ax = 0.f, ay = 0.f;
    for (int i = s + w; i < e; i += 4) {
        unsigned u = HB[(size_t)i * 64 + lane];
        ax += bf_lo(u); ay += bf_hi(u);
    }
    part[w][lane * 2] = ax;
    part[w][lane * 2 + 1] = ay;
    __syncthreads();
    if (threadIdx.x < 128) {
        float sum = part[0][threadIdx.x] + part[1][threadIdx.x]
                  + part[2][threadIdx.x] + part[3][threadIdx.x];
        float c = (float)(e - s);
        outp[g * 128 + threadIdx.x] = sum / fmaxf(c, 1.0f);
    }
}

extern "C" void kernel_launch(void* const* d_in, const int* in_sizes, int n_in,
                              void* d_out, int out_size, void* d_ws, size_t ws_size,
                              hipStream_t stream) {
    const float* x     = (const float*)d_in[0];
    const int*   ei    = (const int*)d_in[1];
    const float* ew    = (const float*)d_in[2];
    const int*   batch = (const int*)d_in[3];
    const float* Wt[3] = {(const float*)d_in[4], (const float*)d_in[6], (const float*)d_in[8]};
    const float* bt[3] = {(const float*)d_in[5], (const float*)d_in[7], (const float*)d_in[9]};
    float* out = (float*)d_out;

    const int D = 128;
    const int N = in_sizes[0] / D;       // 100000
    const int E = in_sizes[2];           // 1600000
    const int G = out_size / (3 * D);    // 256

    // workspace carve-up (256 B aligned)
    char* p = (char*)d_ws;
    auto alloc = [&](size_t bytes) {
        void* r = (void*)p;
        p += (bytes + 255) & ~(size_t)255;
        return r;
    };
    int*      cnt    = (int*)alloc((size_t)N * 4);
    int*      ptr    = (int*)alloc((size_t)(N + 1) * 4);
    int*      pre    = (int*)alloc((size_t)N * 4);
    int*      bsum   = (int*)alloc((size_t)128 * 4);
    int*      gb     = (int*)alloc((size_t)(G + 1) * 4);
    float*    dinv   = (float*)alloc((size_t)N * 4);
    ushort*   WbT    = (ushort*)alloc((size_t)3 * 16384 * 2);
    int2*     csr    = (int2*)alloc((size_t)E * 8);
    unsigned* xb     = (unsigned*)alloc((size_t)N * 64 * 4);  // x,  bf16-packed
    unsigned* bufHL  = (unsigned*)alloc((size_t)N * 64 * 4);  // hl, bf16-packed
    unsigned* bufH   = (unsigned*)alloc((size_t)N * 64 * 4);  // h,  bf16-packed
    int*      epos   = (int*)bufH;   // alias: epos dead before bufH first write

    int nb = (N + 1023) / 1024;
    int prepWork = N > 3 * 16384 ? N : 3 * 16384;

    k_prep<<<(prepWork + 255) / 256, 256, 0, stream>>>(cnt, N, batch, gb, G,
                                                       Wt[0], Wt[1], Wt[2], WbT);
    k_phase1<<<(E + 255) / 256, 256, 0, stream>>>(ei, cnt, epos, E,
                                                  (const float4*)x, (uint2*)xb, N * 32);
    k_scan1<<<nb, 1024, 0, stream>>>(cnt, pre, bsum, N);
    k_scan2<<<1, 128, 0, stream>>>(bsum, nb, ptr, N);
    k_scatter<<<(E + 255) / 256, 256, 0, stream>>>(ei, ew, pre, bsum, ptr, epos,
                                                   csr, E, N);
    k_degdinv<<<(N + 7) / 8, 256, 0, stream>>>(csr, ptr, dinv, N);
    k_norm<<<(N + 7) / 8, 256, 0, stream>>>(csr, ptr, dinv, N);

    for (int l = 0; l < 3; l++) {
        const unsigned* hin = (l == 0) ? xb : bufH;
        k_gemm_mfma<<<(N + 127) / 128, 256, 0, stream>>>(hin, WbT + (size_t)l * 16384,
                                                         bufHL, N);
        k_agg<<<(N + 3) / 4, 256, 0, stream>>>(bufHL, ptr, csr, dinv, bt[l], bufH, N);
        k_pool<<<G, 256, 0, stream>>>(bufH, gb, out + (size_t)l * G * D);
    }
}

// Round 12
// 568.232 us; speedup vs baseline: 2.4034x; 1.0792x over previous
//
#include <hip/hip_runtime.h>

// ---------------------------------------------------------------------------
// GCN block: 3 x (GCNConv -> ReLU -> global_mean_pool)
// 12 dispatches (gaps cost ~9us each; cooperative grid.sync measured ~100us
// per sync on 8-XCD MI355X (R9) — plain dispatches win):
//   k_prep:      zero cnt/bsum + graph bounds + WbT transpose/cast
//   k_phase1:    heterogeneous: blocks[0..782) = layer-1 MFMA GEMM reading
//                fp32 x with in-register bf16 cast; blocks[782..) = the ONLY
//                atomic pass epos[e]=atomicAdd(cnt[col],1)
//   k_scan1:     per-block exclusive scan (pre) + raw block sums (bsum)
//   k_scatter:   inline LDS scan of 128 block sums; csr scatter; ptrv
//   k_degdinv:   half-wave per node, coalesced bucket reads, shfl reduce
//   k_norm:      csr.y = dinv[r]*w*dinv[c], half-wave per node
//   per layer:   k_agg (paired-edge gather, R8-proven loop) ->
//                k_gemm_pool (next-layer GEMM + previous-layer pool fused;
//                final call is pool-only with nbGemm=0)
// ---------------------------------------------------------------------------

typedef short short8 __attribute__((ext_vector_type(8)));   // 8 bf16 (4 VGPR)
typedef float f32x4  __attribute__((ext_vector_type(4)));   // MFMA C/D

__device__ inline unsigned pack_bf16x2(float a, float b) {
    unsigned ua = __float_as_uint(a);
    ua = (ua + 0x7FFFu + ((ua >> 16) & 1u)) >> 16;       // RNE
    unsigned ub = __float_as_uint(b);
    ub = (ub + 0x7FFFu + ((ub >> 16) & 1u)) >> 16;
    return ua | (ub << 16);
}
__device__ inline ushort bf16_1(float a) {
    unsigned ua = __float_as_uint(a);
    return (ushort)((ua + 0x7FFFu + ((ua >> 16) & 1u)) >> 16);
}
__device__ inline float bf_lo(unsigned u) { return __uint_as_float(u << 16); }
__device__ inline float bf_hi(unsigned u) { return __uint_as_float(u & 0xFFFF0000u); }

// ---- shared device bodies -------------------------------------------------

// One block = 128 rows x 128 cols of hl = H @ W (v_mfma_f32_16x16x32_bf16).
// Wave = 32 rows: 2 m-strips x 8 n-tiles, 64 MFMAs. A-frag 16B/lane
// contiguous (F32IN: 32B fp32 -> in-register bf16 cast). B from WbT[n][k].
// Epilogue via LDS (sOut, 8192 u32) -> coalesced u32 stores.
template <bool F32IN>
__device__ __forceinline__ void gemm_tile(const void* __restrict__ Hin,
                                          const ushort* __restrict__ WbT,
                                          unsigned* __restrict__ O, int M,
                                          int bid, unsigned* sOut) {
    int lane = threadIdx.x & 63;
    int wv = threadIdx.x >> 6;
    int quad = lane >> 4;
    int mrow = lane & 15;
    int m0 = bid * 128 + wv * 32;
    int r0 = m0 + mrow;
    int r1 = r0 + 16;
    int r0c = r0 < M ? r0 : M - 1;             // clamp loads, guard stores
    int r1c = r1 < M ? r1 : M - 1;

    short8 a0[4], a1[4];
    if (F32IN) {
        const float* Hf = (const float*)Hin;
#pragma unroll
        for (int s = 0; s < 4; s++) {          // k-step s covers k in [32s,32s+32)
            const float4* p0 = (const float4*)(Hf + (size_t)r0c * 128 + s * 32 + quad * 8);
            const float4* p1 = (const float4*)(Hf + (size_t)r1c * 128 + s * 32 + quad * 8);
            float4 f0 = p0[0], f1 = p0[1];
            float4 g0 = p1[0], g1 = p1[1];
            union { short8 s8; unsigned u[4]; } t0, t1;
            t0.u[0] = pack_bf16x2(f0.x, f0.y); t0.u[1] = pack_bf16x2(f0.z, f0.w);
            t0.u[2] = pack_bf16x2(f1.x, f1.y); t0.u[3] = pack_bf16x2(f1.z, f1.w);
            t1.u[0] = pack_bf16x2(g0.x, g0.y); t1.u[1] = pack_bf16x2(g0.z, g0.w);
            t1.u[2] = pack_bf16x2(g1.x, g1.y); t1.u[3] = pack_bf16x2(g1.z, g1.w);
            a0[s] = t0.s8; a1[s] = t1.s8;
        }
    } else {
        const unsigned* Hb = (const unsigned*)Hin;
#pragma unroll
        for (int s = 0; s < 4; s++) {
            a0[s] = *(const short8*)(Hb + (size_t)r0c * 64 + s * 16 + quad * 4);
            a1[s] = *(const short8*)(Hb + (size_t)r1c * 64 + s * 16 + quad * 4);
        }
    }
    f32x4 acc0[8], acc1[8];
#pragma unroll
    for (int t = 0; t < 8; t++) {
        acc0[t] = (f32x4){0.f, 0.f, 0.f, 0.f};
        acc1[t] = (f32x4){0.f, 0.f, 0.f, 0.f};
    }
#pragma unroll
    for (int s = 0; s < 4; s++) {
#pragma unroll
        for (int t = 0; t < 8; t++) {
            short8 b = *(const short8*)(WbT + (t * 16 + mrow) * 128 + s * 32 + quad * 8);
            acc0[t] = __builtin_amdgcn_mfma_f32_16x16x32_bf16(a0[s], b, acc0[t], 0, 0, 0);
            acc1[t] = __builtin_amdgcn_mfma_f32_16x16x32_bf16(a1[s], b, acc1[t], 0, 0, 0);
        }
    }
    // C/D layout: col = lane&15, row = quad*4 + reg.
    ushort* so = (ushort*)(sOut + wv * 32 * 64);
#pragma unroll
    for (int t = 0; t < 8; t++) {
#pragma unroll
        for (int r = 0; r < 4; r++) {
            int lr = quad * 4 + r;
            int c = t * 16 + mrow;
            so[lr * 128 + c] = bf16_1(acc0[t][r]);
            so[(lr + 16) * 128 + c] = bf16_1(acc1[t][r]);
        }
    }
    __syncthreads();
    const unsigned* si = sOut + wv * 32 * 64;
#pragma unroll 8
    for (int r = 0; r < 32; r++) {
        int row = m0 + r;
        if (row < M) O[(size_t)row * 64 + lane] = si[r * 64 + lane];
    }
}

// One block per graph: stream the sorted node segment, 4 waves stride it,
// LDS-combine (part = 512 floats), divide by count, write. No atomics.
__device__ __forceinline__ void pool_tile(const unsigned* __restrict__ HB,
                                          const int* __restrict__ gb,
                                          float* __restrict__ outp, int g,
                                          float* part) {
    int lane = threadIdx.x & 63, w = threadIdx.x >> 6;
    int s = gb[g], e = gb[g + 1];
    float ax = 0.f, ay = 0.f;
    for (int i = s + w; i < e; i += 4) {
        unsigned u = HB[(size_t)i * 64 + lane];
        ax += bf_lo(u); ay += bf_hi(u);
    }
    part[w * 128 + lane * 2] = ax;
    part[w * 128 + lane * 2 + 1] = ay;
    __syncthreads();
    if (threadIdx.x < 128) {
        float sum = part[threadIdx.x] + part[128 + threadIdx.x]
                  + part[256 + threadIdx.x] + part[384 + threadIdx.x];
        float c = (float)(e - s);
        outp[g * 128 + threadIdx.x] = sum / fmaxf(c, 1.0f);
    }
}

// ---- kernels --------------------------------------------------------------

// Fused pre-pass: zero cnt + bsum, graph bounds, W transpose+cast.
__global__ void k_prep(int* __restrict__ cnt, int N, int* __restrict__ bsum,
                       const int* __restrict__ batch, int* __restrict__ gb, int G,
                       const float* __restrict__ W0, const float* __restrict__ W1,
                       const float* __restrict__ W2, ushort* __restrict__ WbT) {
    int id = blockIdx.x * blockDim.x + threadIdx.x;
    if (id < N) cnt[id] = 0;
    if (id < 128) bsum[id] = 0;
    if (id <= G) {
        int lo = 0, hi = N;
        while (lo < hi) { int mid = (lo + hi) >> 1; if (batch[mid] < id) lo = mid + 1; else hi = mid; }
        gb[id] = lo;
    }
    if (id < 3 * 16384) {
        int l = id >> 14;
        const float* W = (l == 0) ? W0 : ((l == 1) ? W1 : W2);
        int id2 = id & 16383;
        int n = id2 & 127, k = id2 >> 7;
        WbT[l * 16384 + n * 128 + k] = bf16_1(W[k * 128 + n]);
    }
}

// Heterogeneous: blocks[0..nbGemm) = layer-1 GEMM (fp32 x, in-reg bf16 cast);
// blocks[nbGemm..) = the only atomic pass (per-edge bucket rank).
__global__ __launch_bounds__(256) void k_phase1(const int* __restrict__ ei,
                                                int* __restrict__ cnt,
                                                int* __restrict__ epos, int E,
                                                const float* __restrict__ x,
                                                const ushort* __restrict__ WbT,
                                                unsigned* __restrict__ O, int M,
                                                int nbGemm) {
    __shared__ unsigned sBuf[8192];            // 32 KB (gemm epilogue)
    if (blockIdx.x < nbGemm) {
        gemm_tile<true>(x, WbT, O, M, blockIdx.x, sBuf);
        return;
    }
    int tid = (blockIdx.x - nbGemm) * 256 + threadIdx.x;
    if (tid < E) {
        int c = ei[E + tid];
        epos[tid] = atomicAdd(&cnt[c], 1);
    }
}

// Per-block exclusive scan of cnt -> pre, raw block totals -> bsum.
__global__ __launch_bounds__(1024) void k_scan1(const int* __restrict__ cnt,
                                                int* __restrict__ pre,
                                                int* __restrict__ bsum, int n) {
    __shared__ int wsum[16];
    int t = threadIdx.x, lane = t & 63, w = t >> 6;
    int i = blockIdx.x * 1024 + t;
    int v = (i < n) ? cnt[i] : 0;
    int x = v;
#pragma unroll
    for (int off = 1; off < 64; off <<= 1) {
        int y = __shfl_up(x, off, 64);
        if (lane >= off) x += y;
    }
    if (lane == 63) wsum[w] = x;
    __syncthreads();
    int woff = 0, tot = 0;
#pragma unroll
    for (int q = 0; q < 16; q++) { int s = wsum[q]; if (q < w) woff += s; tot += s; }
    if (i < n) pre[i] = woff + x - v;
    if (t == 0) bsum[blockIdx.x] = tot;
}

// Scatter edges to CSR slots. Each block scans the 128 raw block sums in LDS
// (scan2 folded in); also materializes ptrv[i] and ptrv[N].
__global__ __launch_bounds__(256) void k_scatter(const int* __restrict__ ei,
                                                 const float* __restrict__ ew,
                                                 const int* __restrict__ pre,
                                                 const int* __restrict__ bsumRaw,
                                                 int* __restrict__ ptrv,
                                                 const int* __restrict__ epos,
                                                 int2* __restrict__ csr, int E, int N) {
    __shared__ int sRaw[256];
    __shared__ int sPre[256];
    __shared__ int sWt[4];
    int t = threadIdx.x;
    sRaw[t] = (t < 128) ? bsumRaw[t] : 0;
    __syncthreads();
    int lane = t & 63, w2 = t >> 6;
    int v = sRaw[t];
    int x = v;
#pragma unroll
    for (int off = 1; off < 64; off <<= 1) {
        int y = __shfl_up(x, off, 64);
        if (lane >= off) x += y;
    }
    if (lane == 63) sWt[w2] = x;
    __syncthreads();
    int base = 0;
#pragma unroll
    for (int q = 0; q < 4; q++) { if (q < w2) base += sWt[q]; }
    sPre[t] = base + x - v;                    // exclusive prefix of block sums
    __syncthreads();
    int e = blockIdx.x * 256 + t;
    if (e < N) ptrv[e] = pre[e] + sPre[e >> 10];
    if (e == 0) ptrv[N] = sWt[0] + sWt[1];     // grand total (sums in waves 0/1)
    if (e >= E) return;
    int r = ei[e];
    int c = ei[E + e];
    int2 mv; mv.x = r; mv.y = __float_as_int(ew[e]);
    csr[pre[c] + sPre[c >> 10] + epos[e]] = mv;
}

// deg = 1 (self-loop) + sum of bucket weights; dinv = rsqrt(deg).
__global__ __launch_bounds__(256) void k_degdinv(const int2* __restrict__ csr,
                                                 const int* __restrict__ ptrv,
                                                 float* __restrict__ dinv, int N) {
    int node = blockIdx.x * 8 + (threadIdx.x >> 5);
    int j = threadIdx.x & 31;
    if (node >= N) return;
    int e0 = ptrv[node], e1 = ptrv[node + 1];
    float s = (j == 0) ? 1.0f : 0.0f;
    for (int e = e0 + j; e < e1; e += 32) s += __int_as_float(csr[e].y);
#pragma unroll
    for (int off = 1; off < 32; off <<= 1) s += __shfl_xor(s, off, 64);
    if (j == 0) dinv[node] = rsqrtf(s);
}

// csr.y = dinv[r] * w * dinv[c]. Half-wave per node, coalesced int2 RMW.
__global__ __launch_bounds__(256) void k_norm(int2* __restrict__ csr,
                                              const int* __restrict__ ptrv,
                                              const float* __restrict__ dinv, int N) {
    int node = blockIdx.x * 8 + (threadIdx.x >> 5);
    int j = threadIdx.x & 31;
    if (node >= N) return;
    float dc = dinv[node];
    int e0 = ptrv[node], e1 = ptrv[node + 1];
    for (int e = e0 + j; e < e1; e += 32) {
        int2 m = csr[e];
        m.y = __float_as_int(dinv[m.x] * __int_as_float(m.y) * dc);
        csr[e] = m;
    }
}

// One wave per node, paired-edge (R8-proven loop: 4 pairs = 8 edges/iter).
__global__ __launch_bounds__(256) void k_agg(const unsigned* __restrict__ HL,
                                             const int* __restrict__ ptr,
                                             const int2* __restrict__ csr,
                                             const float* __restrict__ dinv,
                                             const float* __restrict__ bias,
                                             unsigned* __restrict__ Hout, int M) {
    __shared__ int2 sM[4 * 64];
    int node = (int)((blockIdx.x * blockDim.x + threadIdx.x) >> 6);
    if (node >= M) return;
    int lane = threadIdx.x & 63;
    int half = lane >> 5;                 // 0: even edges, 1: odd edges
    int q = lane & 31;                    // features 4q .. 4q+3
    int2* mbase = &sM[(threadIdx.x >> 6) * 64];
    int e0 = ptr[node], e1 = ptr[node + 1];
    int deg = e1 - e0;
    int nbv = deg < 64 ? deg : 64;
    if (lane < nbv) mbase[lane] = csr[e0 + lane];   // one coalesced load
    const uint2* HL2 = (const uint2*)HL;            // row = 32 uint2
    float di = dinv[node];
    float sn = (half == 0) ? di * di : 0.f;         // self-loop on half 0 only
    uint2 us = HL2[(size_t)node * 32 + q];
    float a0 = sn * bf_lo(us.x), a1 = sn * bf_hi(us.x);
    float a2 = sn * bf_lo(us.y), a3 = sn * bf_hi(us.y);
    int j = half;
    for (; j + 8 <= nbv; j += 8) {                  // 4 pairs in flight
        int2 m[4]; uint2 u[4];
#pragma unroll
        for (int t = 0; t < 4; t++) m[t] = mbase[j + 2 * t];
#pragma unroll
        for (int t = 0; t < 4; t++) u[t] = HL2[(size_t)m[t].x * 32 + q];
#pragma unroll
        for (int t = 0; t < 4; t++) {
            float nv = __int_as_float(m[t].y);
            a0 += nv * bf_lo(u[t].x); a1 += nv * bf_hi(u[t].x);
            a2 += nv * bf_lo(u[t].y); a3 += nv * bf_hi(u[t].y);
        }
    }
    for (; j < nbv; j += 2) {
        int2 m = mbase[j];
        uint2 u = HL2[(size_t)m.x * 32 + q];
        float nv = __int_as_float(m.y);
        a0 += nv * bf_lo(u.x); a1 += nv * bf_hi(u.x);
        a2 += nv * bf_lo(u.y); a3 += nv * bf_hi(u.y);
    }
    for (int e = e0 + 64 + half; e < e1; e += 2) {  // rare high-degree tail
        int2 m = csr[e];
        uint2 u = HL2[(size_t)m.x * 32 + q];
        float nv = __int_as_float(m.y);
        a0 += nv * bf_lo(u.x); a1 += nv * bf_hi(u.x);
        a2 += nv * bf_lo(u.y); a3 += nv * bf_hi(u.y);
    }
    a0 += __shfl_xor(a0, 32, 64);
    a1 += __shfl_xor(a1, 32, 64);
    a2 += __shfl_xor(a2, 32, 64);
    a3 += __shfl_xor(a3, 32, 64);
    float4 bv = ((const float4*)bias)[q];
    float r0 = fmaxf(a0 + bv.x, 0.f);
    float r1 = fmaxf(a1 + bv.y, 0.f);
    float r2 = fmaxf(a2 + bv.z, 0.f);
    float r3 = fmaxf(a3 + bv.w, 0.f);
    if (half == 0) {
        uint2 pv;
        pv.x = pack_bf16x2(r0, r1);
        pv.y = pack_bf16x2(r2, r3);
        ((uint2*)(Hout + (size_t)node * 64))[q] = pv;
    }
}

// Heterogeneous: blocks[0..nbGemm) = next-layer GEMM reading Hb;
// blocks[nbGemm..nbGemm+G) = pool of the SAME Hb into outp (both depend only
// on the preceding agg). nbGemm=0 -> pool-only (final layer).
__global__ __launch_bounds__(256) void k_gemm_pool(const unsigned* __restrict__ Hb,
                                                   const ushort* __restrict__ WbT,
                                                   unsigned* __restrict__ O, int M,
                                                   const int* __restrict__ gb,
                                                   float* __restrict__ outp,
                                                   int nbGemm) {
    __shared__ unsigned sBuf[8192];            // gemm epilogue / pool partials
    if (blockIdx.x < nbGemm) {
        gemm_tile<false>(Hb, WbT, O, M, blockIdx.x, sBuf);
        return;
    }
    pool_tile(Hb, gb, outp, blockIdx.x - nbGemm, (float*)sBuf);
}

extern "C" void kernel_launch(void* const* d_in, const int* in_sizes, int n_in,
                              void* d_out, int out_size, void* d_ws, size_t ws_size,
                              hipStream_t stream) {
    const float* x     = (const float*)d_in[0];
    const int*   ei    = (const int*)d_in[1];
    const float* ew    = (const float*)d_in[2];
    const int*   batch = (const int*)d_in[3];
    const float* Wt[3] = {(const float*)d_in[4], (const float*)d_in[6], (const float*)d_in[8]};
    const float* bt[3] = {(const float*)d_in[5], (const float*)d_in[7], (const float*)d_in[9]};
    float* out = (float*)d_out;

    const int D = 128;
    const int N = in_sizes[0] / D;       // 100000
    const int E = in_sizes[2];           // 1600000
    const int G = out_size / (3 * D);    // 256

    // workspace carve-up (256 B aligned)
    char* p = (char*)d_ws;
    auto alloc = [&](size_t bytes) {
        void* r = (void*)p;
        p += (bytes + 255) & ~(size_t)255;
        return r;
    };
    int*      cnt    = (int*)alloc((size_t)N * 4);
    int*      ptr    = (int*)alloc((size_t)(N + 1) * 4);
    int*      pre    = (int*)alloc((size_t)N * 4);
    int*      bsum   = (int*)alloc((size_t)128 * 4);
    int*      gb     = (int*)alloc((size_t)(G + 1) * 4);
    float*    dinv   = (float*)alloc((size_t)N * 4);
    ushort*   WbT    = (ushort*)alloc((size_t)3 * 16384 * 2);
    int2*     csr    = (int2*)alloc((size_t)E * 8);
    unsigned* bufHL  = (unsigned*)alloc((size_t)N * 64 * 4);  // hl, bf16-packed
    unsigned* bufH   = (unsigned*)alloc((size_t)N * 64 * 4);  // h,  bf16-packed
    int*      epos   = (int*)bufH;   // alias: epos dead before bufH first write

    int nb = (N + 1023) / 1024;                 // 98 scan blocks (<=128)
    int nbGemm = (N + 127) / 128;               // 782 gemm blocks
    int nbAtomic = (E + 255) / 256;             // 6250 atomic blocks
    int prepWork = N > 3 * 16384 ? N : 3 * 16384;

    k_prep<<<(prepWork + 255) / 256, 256, 0, stream>>>(cnt, N, bsum, batch, gb, G,
                                                       Wt[0], Wt[1], Wt[2], WbT);
    // layer-1 GEMM fused with the atomic pass (independent inputs)
    k_phase1<<<nbGemm + nbAtomic, 256, 0, stream>>>(ei, cnt, epos, E,
                                                    x, WbT, bufHL, N, nbGemm);
    k_scan1<<<nb, 1024, 0, stream>>>(cnt, pre, bsum, N);
    k_scatter<<<(E + 255) / 256, 256, 0, stream>>>(ei, ew, pre, bsum, ptr, epos,
                                                   csr, E, N);
    k_degdinv<<<(N + 7) / 8, 256, 0, stream>>>(csr, ptr, dinv, N);
    k_norm<<<(N + 7) / 8, 256, 0, stream>>>(csr, ptr, dinv, N);

    // L1 aggregate, then fused (gemm_{l+1} + pool_l), final pool-only.
    k_agg<<<(N + 3) / 4, 256, 0, stream>>>(bufHL, ptr, csr, dinv, bt[0], bufH, N);
    k_gemm_pool<<<nbGemm + G, 256, 0, stream>>>(bufH, WbT + 16384, bufHL, N,
                                                gb, out + 0 * (size_t)G * D, nbGemm);
    k_agg<<<(N + 3) / 4, 256, 0, stream>>>(bufHL, ptr, csr, dinv, bt[1], bufH, N);
    k_gemm_pool<<<nbGemm + G, 256, 0, stream>>>(bufH, WbT + 2 * 16384, bufHL, N,
                                                gb, out + 1 * (size_t)G * D, nbGemm);
    k_agg<<<(N + 3) / 4, 256, 0, stream>>>(bufHL, ptr, csr, dinv, bt[2], bufH, N);
    k_gemm_pool<<<G, 256, 0, stream>>>(bufH, WbT, nullptr, 0,
                                       gb, out + 2 * (size_t)G * D, 0);
}